// Round 1
// baseline (308.092 us; speedup 1.0000x reference)
//
#include <hip/hip_runtime.h>
#include <math.h>

// ---------------- compile-time 64-point twiddle tables ----------------
struct cf2 { float x, y; };
struct TW64 { float c[64], s[64]; };
struct CF2T { cf2 v[64]; };

constexpr double PI_D = 3.14159265358979323846264338327950288;

constexpr double tsin(double x){
  double x2 = x*x, r = x, t = x;
  t *= -x2/6.0;   r += t;
  t *= -x2/20.0;  r += t;
  t *= -x2/42.0;  r += t;
  t *= -x2/72.0;  r += t;
  t *= -x2/110.0; r += t;
  t *= -x2/156.0; r += t;
  t *= -x2/210.0; r += t;
  t *= -x2/272.0; r += t;
  return r;
}
constexpr double tcos(double x){
  double x2 = x*x, r = 1.0, t = 1.0;
  t *= -x2/2.0;   r += t;
  t *= -x2/12.0;  r += t;
  t *= -x2/30.0;  r += t;
  t *= -x2/56.0;  r += t;
  t *= -x2/90.0;  r += t;
  t *= -x2/132.0; r += t;
  t *= -x2/182.0; r += t;
  t *= -x2/240.0; r += t;
  return r;
}
// cos/sin(2*pi*j/64) via quadrant reduction
constexpr double ang_cos(int j){
  int r = j & 15, q = (j >> 4) & 3;
  double a = PI_D/32.0 * r;
  double cc = tcos(a), ss = tsin(a);
  return q==0 ? cc : q==1 ? -ss : q==2 ? -cc : ss;
}
constexpr double ang_sin(int j){
  int r = j & 15, q = (j >> 4) & 3;
  double a = PI_D/32.0 * r;
  double cc = tcos(a), ss = tsin(a);
  return q==0 ? ss : q==1 ? cc : q==2 ? -ss : -cc;
}
constexpr TW64 make_tw(){
  TW64 t{};
  for (int j=0;j<64;j++){ t.c[j] = (float)ang_cos(j); t.s[j] = (float)ang_sin(j); }
  return t;
}
constexpr CF2T make_twi(){
  CF2T r{};
  for (int j=0;j<64;j++){ r.v[j].x = (float)ang_cos(j); r.v[j].y = (float)ang_sin(j); }
  return r;
}
constexpr CF2T make_pq(){
  CF2T r{};
  for (int j=0;j<64;j++){
    double c = ang_cos(j), s = ang_sin(j);
    r.v[j].x = (float)((c + s) / 262144.0);  // (cos+sin)/64^3
    r.v[j].y = (float)((s - c) / 262144.0);  // (sin-cos)/64^3
  }
  return r;
}

constexpr TW64 TWct = make_tw();        // constant-folded literals (unrolled loops)
__constant__ CF2T TWIdev = make_twi();  // runtime (c,s) lookups
__constant__ CF2T PQdev  = make_pq();   // inverse last-stage coefficients, scale folded

// ---------------- K1: forward n3->k3 (8 modes) and n2->k2 (16 modes) ----------------
// grid = (b*64+ci)*16 + n1g  (2048 blocks), 256 threads
// out: y2g[bc][n1][k2i][k3] float2   (8 MiB)
__global__ __launch_bounds__(256) void k_fwd(const float* __restrict__ x, float2* __restrict__ y2g){
  __shared__ float2 y1[8][4][65];   // [k3][n1l][n2], padded
  __shared__ cf2 twl[64];
  int bid = blockIdx.x;
  int n1g = bid & 15, ci_b = bid >> 4;   // ci_b = b*64+ci
  int t = threadIdx.x;
  if (t < 64) twl[t] = TWIdev.v[t];
  int n1l = t >> 6, n2 = t & 63;
  int n1 = n1g*4 + n1l;
  const float4* xrow = (const float4*)(x + (((size_t)(ci_b*64 + n1))*64 + n2)*64);
  float xr[64];
  #pragma unroll
  for (int i=0;i<16;i++){
    float4 v = xrow[i];
    xr[4*i]=v.x; xr[4*i+1]=v.y; xr[4*i+2]=v.z; xr[4*i+3]=v.w;
  }
  float yr[8], yi[8];
  #pragma unroll
  for (int k=0;k<8;k++){ yr[k]=0.f; yi[k]=0.f; }
  #pragma unroll
  for (int n3=0;n3<64;n3++){
    float xv = xr[n3];
    #pragma unroll
    for (int k=0;k<8;k++){
      // constant indices after unroll -> literal operands, no loads
      yr[k] = fmaf(xv,  TWct.c[(k*n3)&63], yr[k]);
      yi[k] = fmaf(xv, -TWct.s[(k*n3)&63], yi[k]);
    }
  }
  #pragma unroll
  for (int k=0;k<8;k++) y1[k][n1l][n2] = make_float2(yr[k], yi[k]);
  __syncthreads();
  // stage C: n2 -> k2 (16 modes), wave w handles k2i = 4w..4w+3
  int w = t >> 6, lane = t & 63;
  int n1c = lane >> 4, k3c = (lane >> 1) & 7, half = lane & 1;
  #pragma unroll
  for (int kk=0;kk<4;kk++){
    int k2i = w*4 + kk;
    int k2 = k2i < 8 ? k2i : 48 + k2i;
    int idx = (k2 * (half*32)) & 63;
    float ar = 0.f, ai = 0.f;
    #pragma unroll 8
    for (int i=0;i<32;i++){
      cf2 tw = twl[idx];
      idx = (idx + k2) & 63;
      float2 y = y1[k3c][n1c][half*32 + i];
      ar = fmaf(y.x, tw.x, fmaf(y.y, tw.y, ar));
      ai = fmaf(y.y, tw.x, fmaf(-y.x, tw.y, ai));
    }
    ar += __shfl_xor(ar, 1, 64);
    ai += __shfl_xor(ai, 1, 64);
    if (half == 0){
      int n1w = n1g*4 + n1c;
      y2g[((size_t)(ci_b*64 + n1w)*16 + k2i)*8 + k3c] = make_float2(ar, ai);
    }
  }
}

// ---------------- K2: forward n1->k1 (16 modes) + xh + cos_phase ----------------
// grid = b*64+ci (128 blocks), 256 threads
template<int K1B>
__device__ __forceinline__ void k2_body(const float2 (*yl)[128], int kk, float* ar, float* ai){
  for (int n1=0;n1<64;n1++){
    float2 y = yl[n1][kk];
    #pragma unroll
    for (int j=0;j<8;j++){
      int k1i = K1B + 2*j;                 // constant after unroll
      int k1 = k1i < 8 ? k1i : 48 + k1i;
      cf2 tw = TWIdev.v[(k1*n1)&63];       // uniform index -> s_load
      ar[j] = fmaf(y.x, tw.x, fmaf(y.y, tw.y, ar[j]));
      ai[j] = fmaf(y.y, tw.x, fmaf(-y.x, tw.y, ai[j]));
    }
  }
}

__global__ __launch_bounds__(256) void k_fwd_n1(const float2* __restrict__ y2g,
                                                float* __restrict__ xh, float* __restrict__ cp){
  __shared__ float2 yl[64][128];   // 64 KiB
  int bc = blockIdx.x;
  int t = threadIdx.x;
  const float2* src = y2g + (size_t)bc * 8192;
  #pragma unroll
  for (int j=0;j<32;j++){
    int idx = t + j*256;
    yl[idx>>7][idx&127] = src[idx];
  }
  __syncthreads();
  int kk = t & 127;
  int k2i = kk >> 3, k3 = kk & 7;
  float ar[8], ai[8];
  #pragma unroll
  for (int j=0;j<8;j++){ ar[j]=0.f; ai[j]=0.f; }
  if (t < 128) k2_body<0>(yl, kk, ar, ai);
  else         k2_body<1>(yl, kk, ar, ai);
  int k1base = t >> 7;
  size_t xbase = (size_t)bc * 2048;
  #pragma unroll
  for (int j=0;j<8;j++){
    int k1i = k1base + 2*j;
    float vr = ar[j], vi = ai[j];
    float vxh = vr - vi;                    // Re - Im
    xh[xbase + k1i*128 + kk] = vxh;
    if (k1i < 8 && k2i < 8){
      int phi = (k1i + k2i + k3) & 63;      // e^{i*2pi*(k1+k2+k3)/64} * conj(X)
      cf2 tw = TWIdev.v[phi];
      float vxhf = vr*(tw.x - tw.y) + vi*(tw.x + tw.y);
      cp[(size_t)bc*512 + k1i*64 + k2i*8 + k3] = cosf(atan2f(vxhf, vxh));
    }
  }
}

// ---------------- K3: per-mode channel mixing (einsum bixyz,ioxyz->boxyz) ----------------
// grid = (blk*64+co)*8 + k1l (2048 blocks), 256 threads
__global__ __launch_bounds__(256) void k_mix(const float* __restrict__ xh,
    const float* __restrict__ w1, const float* __restrict__ w2,
    const float* __restrict__ w3, const float* __restrict__ w4,
    float* __restrict__ mh){
  __shared__ float xs[2][64][64];   // [b][ci][k2l*8+k3]
  __shared__ float wsh[64][64];     // [ci][k2l*8+k3]
  __shared__ float ps[2][128];
  int bid = blockIdx.x;
  int k1l = bid & 7, co = (bid >> 3) & 63, blk = bid >> 9;
  const float* w = (blk==0) ? w1 : (blk==1) ? w2 : (blk==2) ? w3 : w4;
  int k1i = k1l + ((blk & 1) << 3);
  int k2off = (blk & 2) ? 64 : 0;
  int t = threadIdx.x;
  #pragma unroll
  for (int j=0;j<16;j++){
    int idx = t + j*256;
    int ci = idx >> 6, kk = idx & 63;
    wsh[ci][kk] = w[(size_t)(ci*64 + co)*512 + k1l*64 + kk];
  }
  #pragma unroll
  for (int j=0;j<32;j++){
    int idx = t + j*256;
    int b = idx >> 12, ci = (idx >> 6) & 63, kk = idx & 63;
    xs[b][ci][kk] = xh[(size_t)((b*64 + ci)*16 + k1i)*128 + k2off + kk];
  }
  __syncthreads();
  int half = t >> 7, o = t & 127, b = o >> 6, kk = o & 63;
  float acc = 0.f;
  #pragma unroll 8
  for (int i=0;i<32;i++){
    int ci = half*32 + i;
    acc = fmaf(xs[b][ci][kk], wsh[ci][kk], acc);
  }
  ps[half][o] = acc;
  __syncthreads();
  if (t < 128){
    int b2 = t >> 6, kk2 = t & 63;
    mh[(size_t)((b2*64 + co)*16 + k1i)*128 + k2off + kk2] = ps[0][t] + ps[1][t];
  }
}

// ---------------- K4: fused inverse DHT (sparse modes) + cos_phase + store ----------------
// grid = (b*64+co)*64 + n1 (8192 blocks), 256 threads
__global__ __launch_bounds__(256) void k_inv(const float* __restrict__ mh,
                                             const float* __restrict__ cp,
                                             float* __restrict__ out){
  __shared__ float ml[2048];
  __shared__ float2 z1[16][8];
  __shared__ float2 z2[64][8];
  __shared__ cf2 twl[64];
  __shared__ cf2 pql[64];
  int bid = blockIdx.x;
  int n1 = bid & 63, bc = bid >> 6;
  int t = threadIdx.x;
  if (t < 64){ twl[t] = TWIdev.v[t]; pql[t] = PQdev.v[t]; }
  const float* src = mh + (size_t)bc * 2048;
  #pragma unroll
  for (int j=0;j<8;j++) ml[t + j*256] = src[t + j*256];
  __syncthreads();
  // k1 -> n1 (this block's n1 only)
  if (t < 128){
    float zr = 0.f, zi = 0.f;
    #pragma unroll
    for (int k1i=0;k1i<16;k1i++){
      int k1 = k1i < 8 ? k1i : 48 + k1i;
      cf2 tw = TWIdev.v[(k1*n1)&63];   // uniform -> s_load
      float m = ml[k1i*128 + t];
      zr = fmaf(m, tw.x, zr);
      zi = fmaf(m, -tw.y, zi);
    }
    z1[t>>3][t&7] = make_float2(zr, zi);
  }
  __syncthreads();
  // k2 -> n2
  #pragma unroll
  for (int jo=0;jo<2;jo++){
    int o = t + jo*256;
    int n2 = o >> 3, k3 = o & 7;
    float zr = 0.f, zi = 0.f;
    #pragma unroll
    for (int k2i=0;k2i<16;k2i++){
      int k2 = k2i < 8 ? k2i : 48 + k2i;
      cf2 tw = twl[(k2*n2)&63];
      float2 z = z1[k2i][k3];
      zr = fmaf(z.x, tw.x, fmaf(z.y, tw.y, zr));
      zi = fmaf(z.y, tw.x, fmaf(-z.x, tw.y, zi));
    }
    z2[n2][k3] = make_float2(zr, zi);
  }
  __syncthreads();
  // k3 -> n3 (Re - Im folded into p/q with 1/64^3), + cos_phase corner, store
  int n3 = t & 63;
  int n2base = (t >> 6) * 16;
  float p[8], q[8];
  #pragma unroll
  for (int k3=0;k3<8;k3++){
    cf2 pq = pql[(k3*n3)&63];
    p[k3] = pq.x; q[k3] = pq.y;
  }
  float* orow = out + ((size_t)bc*64 + n1)*4096;
  bool corner = (n1 < 8) && (n3 < 8);
  const float* cpr = cp + (size_t)bc*512 + n1*64 + n3;
  #pragma unroll
  for (int j=0;j<16;j++){
    int n2 = n2base + j;
    float v = 0.f;
    #pragma unroll
    for (int k3=0;k3<8;k3++){
      float2 z = z2[n2][k3];
      v = fmaf(z.x, p[k3], fmaf(z.y, q[k3], v));
    }
    if (corner && n2 < 8) v *= cpr[n2*8];
    orow[n2*64 + n3] = v;
  }
}

// ---------------- launch ----------------
extern "C" void kernel_launch(void* const* d_in, const int* in_sizes, int n_in,
                              void* d_out, int out_size, void* d_ws, size_t ws_size,
                              hipStream_t stream) {
  (void)in_sizes; (void)n_in; (void)out_size; (void)ws_size;
  const float* x  = (const float*)d_in[0];
  const float* w1 = (const float*)d_in[1];
  const float* w2 = (const float*)d_in[2];
  const float* w3 = (const float*)d_in[3];
  const float* w4 = (const float*)d_in[4];
  float* out = (float*)d_out;
  char* ws = (char*)d_ws;
  float2* y2g = (float2*)ws;                                   // 8 MiB
  float*  xh  = (float*)(ws + (8u<<20));                       // 1 MiB
  float*  cp  = (float*)(ws + (9u<<20));                       // 256 KiB
  float*  mh  = (float*)(ws + (9u<<20) + (256u<<10));          // 1 MiB

  k_fwd   <<<2048, 256, 0, stream>>>(x, y2g);
  k_fwd_n1<<< 128, 256, 0, stream>>>(y2g, xh, cp);
  k_mix   <<<2048, 256, 0, stream>>>(xh, w1, w2, w3, w4, mh);
  k_inv   <<<8192, 256, 0, stream>>>(mh, cp, out);
}

// Round 2
// 296.704 us; speedup vs baseline: 1.0384x; 1.0384x over previous
//
#include <hip/hip_runtime.h>
#include <math.h>

// ---------------- compile-time 64-point twiddle tables ----------------
struct cf2 { float x, y; };
struct TW64 { float c[64], s[64]; };
struct CF2T { cf2 v[64]; };

constexpr double PI_D = 3.14159265358979323846264338327950288;

constexpr double tsin(double x){
  double x2 = x*x, r = x, t = x;
  t *= -x2/6.0;   r += t;
  t *= -x2/20.0;  r += t;
  t *= -x2/42.0;  r += t;
  t *= -x2/72.0;  r += t;
  t *= -x2/110.0; r += t;
  t *= -x2/156.0; r += t;
  t *= -x2/210.0; r += t;
  t *= -x2/272.0; r += t;
  return r;
}
constexpr double tcos(double x){
  double x2 = x*x, r = 1.0, t = 1.0;
  t *= -x2/2.0;   r += t;
  t *= -x2/12.0;  r += t;
  t *= -x2/30.0;  r += t;
  t *= -x2/56.0;  r += t;
  t *= -x2/90.0;  r += t;
  t *= -x2/132.0; r += t;
  t *= -x2/182.0; r += t;
  t *= -x2/240.0; r += t;
  return r;
}
constexpr double ang_cos(int j){
  int r = j & 15, q = (j >> 4) & 3;
  double a = PI_D/32.0 * r;
  double cc = tcos(a), ss = tsin(a);
  return q==0 ? cc : q==1 ? -ss : q==2 ? -cc : ss;
}
constexpr double ang_sin(int j){
  int r = j & 15, q = (j >> 4) & 3;
  double a = PI_D/32.0 * r;
  double cc = tcos(a), ss = tsin(a);
  return q==0 ? ss : q==1 ? cc : q==2 ? -ss : -cc;
}
constexpr TW64 make_tw(){
  TW64 t{};
  for (int j=0;j<64;j++){ t.c[j] = (float)ang_cos(j); t.s[j] = (float)ang_sin(j); }
  return t;
}
constexpr CF2T make_twi(){
  CF2T r{};
  for (int j=0;j<64;j++){ r.v[j].x = (float)ang_cos(j); r.v[j].y = (float)ang_sin(j); }
  return r;
}
constexpr CF2T make_pq(){
  CF2T r{};
  for (int j=0;j<64;j++){
    double c = ang_cos(j), s = ang_sin(j);
    r.v[j].x = (float)((c + s) / 262144.0);  // (cos+sin)/64^3
    r.v[j].y = (float)((s - c) / 262144.0);  // (sin-cos)/64^3
  }
  return r;
}

constexpr TW64 TWct = make_tw();        // constant-folded literals (unrolled loops)
__constant__ CF2T TWIdev = make_twi();  // runtime (c,s) lookups
__constant__ CF2T PQdev  = make_pq();   // inverse last-stage coefficients, scale folded

// ---------------- K1: forward n3->k3 (8 modes) and n2->k2 (16 modes) ----------------
// grid = (b*64+ci)*64 + n1  (8192 blocks), 256 threads
// out: y2g[bc][n1][k2i][k3] float2   (8 MiB)

template<int G>
__device__ __forceinline__ void stageA(const float* __restrict__ row,
                                       float& r0, float& i0, float& r1, float& i1){
  r0=0.f; i0=0.f; r1=0.f; i1=0.f;
  #pragma unroll
  for (int n3=0;n3<64;n3++){
    float xv = row[n3];
    // constant indices after unroll -> literal operands, no loads
    r0 = fmaf(xv,  TWct.c[((2*G  )*n3)&63], r0);
    i0 = fmaf(xv, -TWct.s[((2*G  )*n3)&63], i0);
    r1 = fmaf(xv,  TWct.c[((2*G+1)*n3)&63], r1);
    i1 = fmaf(xv, -TWct.s[((2*G+1)*n3)&63], i1);
  }
}

__global__ __launch_bounds__(256) void k_fwd(const float* __restrict__ x, float2* __restrict__ y2g){
  __shared__ float xt[64*65];    // [n2][n3], pad 65 -> conflict-free column access
  __shared__ float2 y1[8*66];    // [k3][n2], pad 66 -> k3 spreads banks
  __shared__ cf2 twl[64];
  int bid = blockIdx.x;
  int n1 = bid & 63, ci_b = bid >> 6;   // ci_b = b*64+ci
  int t = threadIdx.x;
  if (t < 64) twl[t] = TWIdev.v[t];

  // coalesced: 16 KB plane, lane-consecutive float4 (1 KB / instruction)
  const float4* src = (const float4*)(x + (size_t)(ci_b*64 + n1)*4096);
  #pragma unroll
  for (int j=0;j<4;j++){
    int q = t + j*256;
    float4 v = src[q];
    int n2 = q >> 4, n3 = (q & 15)*4;
    float* d = &xt[n2*65 + n3];
    d[0]=v.x; d[1]=v.y; d[2]=v.z; d[3]=v.w;
  }
  __syncthreads();

  // stage A: n3 -> k3 (8 modes); thread (n2 = t&63, g = t>>6) does k3 = {2g, 2g+1}
  {
    int n2 = t & 63, g = t >> 6;        // g wave-uniform -> literal twiddles per branch
    const float* row = &xt[n2*65];
    float r0,i0,r1,i1;
    if      (g==0) stageA<0>(row,r0,i0,r1,i1);
    else if (g==1) stageA<1>(row,r0,i0,r1,i1);
    else if (g==2) stageA<2>(row,r0,i0,r1,i1);
    else           stageA<3>(row,r0,i0,r1,i1);
    y1[(2*g  )*66 + n2] = make_float2(r0,i0);
    y1[(2*g+1)*66 + n2] = make_float2(r1,i1);
  }
  __syncthreads();

  // stage B: n2 -> k2 (16 modes); thread (half = t&1, k3 = (t>>1)&7, k2i = t>>4)
  {
    int half = t & 1, k3 = (t >> 1) & 7, k2i = t >> 4;
    int k2 = k2i < 8 ? k2i : 48 + k2i;
    int idx = (k2 * (half*32)) & 63;
    const float2* yrow = &y1[k3*66 + half*32];
    float ar = 0.f, ai = 0.f;
    #pragma unroll 8
    for (int i=0;i<32;i++){
      cf2 tw = twl[idx];
      idx = (idx + k2) & 63;
      float2 y = yrow[i];
      ar = fmaf(y.x, tw.x, fmaf(y.y, tw.y, ar));
      ai = fmaf(y.y, tw.x, fmaf(-y.x, tw.y, ai));
    }
    ar += __shfl_xor(ar, 1, 64);
    ai += __shfl_xor(ai, 1, 64);
    if (half == 0){
      y2g[((size_t)(ci_b*64 + n1)*16 + k2i)*8 + k3] = make_float2(ar, ai);
    }
  }
}

// ---------------- K2: forward n1->k1 (16 modes) + xh + cos_phase ----------------
// grid = b*64+ci (128 blocks), 256 threads
template<int K1B>
__device__ __forceinline__ void k2_body(const float2 (*yl)[128], int kk, float* ar, float* ai){
  for (int n1=0;n1<64;n1++){
    float2 y = yl[n1][kk];
    #pragma unroll
    for (int j=0;j<8;j++){
      int k1i = K1B + 2*j;                 // constant after unroll
      int k1 = k1i < 8 ? k1i : 48 + k1i;
      cf2 tw = TWIdev.v[(k1*n1)&63];       // uniform index -> s_load
      ar[j] = fmaf(y.x, tw.x, fmaf(y.y, tw.y, ar[j]));
      ai[j] = fmaf(y.y, tw.x, fmaf(-y.x, tw.y, ai[j]));
    }
  }
}

__global__ __launch_bounds__(256) void k_fwd_n1(const float2* __restrict__ y2g,
                                                float* __restrict__ xh, float* __restrict__ cp){
  __shared__ float2 yl[64][128];   // 64 KiB
  int bc = blockIdx.x;
  int t = threadIdx.x;
  const float2* src = y2g + (size_t)bc * 8192;
  #pragma unroll
  for (int j=0;j<32;j++){
    int idx = t + j*256;
    yl[idx>>7][idx&127] = src[idx];
  }
  __syncthreads();
  int kk = t & 127;
  int k2i = kk >> 3, k3 = kk & 7;
  float ar[8], ai[8];
  #pragma unroll
  for (int j=0;j<8;j++){ ar[j]=0.f; ai[j]=0.f; }
  if (t < 128) k2_body<0>(yl, kk, ar, ai);
  else         k2_body<1>(yl, kk, ar, ai);
  int k1base = t >> 7;
  size_t xbase = (size_t)bc * 2048;
  #pragma unroll
  for (int j=0;j<8;j++){
    int k1i = k1base + 2*j;
    float vr = ar[j], vi = ai[j];
    float vxh = vr - vi;                    // Re - Im
    xh[xbase + k1i*128 + kk] = vxh;
    if (k1i < 8 && k2i < 8){
      int phi = (k1i + k2i + k3) & 63;      // e^{i*2pi*(k1+k2+k3)/64} * conj(X)
      cf2 tw = TWIdev.v[phi];
      float vxhf = vr*(tw.x - tw.y) + vi*(tw.x + tw.y);
      cp[(size_t)bc*512 + k1i*64 + k2i*8 + k3] = cosf(atan2f(vxhf, vxh));
    }
  }
}

// ---------------- K3: per-mode channel mixing (einsum bixyz,ioxyz->boxyz) ----------------
// grid = (blk*64+co)*8 + k1l (2048 blocks), 256 threads
__global__ __launch_bounds__(256) void k_mix(const float* __restrict__ xh,
    const float* __restrict__ w1, const float* __restrict__ w2,
    const float* __restrict__ w3, const float* __restrict__ w4,
    float* __restrict__ mh){
  __shared__ float xs[2][64][64];   // [b][ci][k2l*8+k3]
  __shared__ float wsh[64][64];     // [ci][k2l*8+k3]
  __shared__ float ps[2][128];
  int bid = blockIdx.x;
  int k1l = bid & 7, co = (bid >> 3) & 63, blk = bid >> 9;
  const float* w = (blk==0) ? w1 : (blk==1) ? w2 : (blk==2) ? w3 : w4;
  int k1i = k1l + ((blk & 1) << 3);
  int k2off = (blk & 2) ? 64 : 0;
  int t = threadIdx.x;
  #pragma unroll
  for (int j=0;j<16;j++){
    int idx = t + j*256;
    int ci = idx >> 6, kk = idx & 63;
    wsh[ci][kk] = w[(size_t)(ci*64 + co)*512 + k1l*64 + kk];
  }
  #pragma unroll
  for (int j=0;j<32;j++){
    int idx = t + j*256;
    int b = idx >> 12, ci = (idx >> 6) & 63, kk = idx & 63;
    xs[b][ci][kk] = xh[(size_t)((b*64 + ci)*16 + k1i)*128 + k2off + kk];
  }
  __syncthreads();
  int half = t >> 7, o = t & 127, b = o >> 6, kk = o & 63;
  float acc = 0.f;
  #pragma unroll 8
  for (int i=0;i<32;i++){
    int ci = half*32 + i;
    acc = fmaf(xs[b][ci][kk], wsh[ci][kk], acc);
  }
  ps[half][o] = acc;
  __syncthreads();
  if (t < 128){
    int b2 = t >> 6, kk2 = t & 63;
    mh[(size_t)((b2*64 + co)*16 + k1i)*128 + k2off + kk2] = ps[0][t] + ps[1][t];
  }
}

// ---------------- K4: fused inverse DHT (sparse modes) + cos_phase + store ----------------
// grid = (b*64+co)*64 + n1 (8192 blocks), 256 threads
__global__ __launch_bounds__(256) void k_inv(const float* __restrict__ mh,
                                             const float* __restrict__ cp,
                                             float* __restrict__ out){
  __shared__ float ml[2048];
  __shared__ float2 z1[16][8];
  __shared__ float2 z2[64][8];
  __shared__ cf2 twl[64];
  __shared__ cf2 pql[64];
  int bid = blockIdx.x;
  int n1 = bid & 63, bc = bid >> 6;
  int t = threadIdx.x;
  if (t < 64){ twl[t] = TWIdev.v[t]; pql[t] = PQdev.v[t]; }
  const float* src = mh + (size_t)bc * 2048;
  #pragma unroll
  for (int j=0;j<8;j++) ml[t + j*256] = src[t + j*256];
  __syncthreads();
  // k1 -> n1 (this block's n1 only)
  if (t < 128){
    float zr = 0.f, zi = 0.f;
    #pragma unroll
    for (int k1i=0;k1i<16;k1i++){
      int k1 = k1i < 8 ? k1i : 48 + k1i;
      cf2 tw = TWIdev.v[(k1*n1)&63];   // uniform -> s_load
      float m = ml[k1i*128 + t];
      zr = fmaf(m, tw.x, zr);
      zi = fmaf(m, -tw.y, zi);
    }
    z1[t>>3][t&7] = make_float2(zr, zi);
  }
  __syncthreads();
  // k2 -> n2
  #pragma unroll
  for (int jo=0;jo<2;jo++){
    int o = t + jo*256;
    int n2 = o >> 3, k3 = o & 7;
    float zr = 0.f, zi = 0.f;
    #pragma unroll
    for (int k2i=0;k2i<16;k2i++){
      int k2 = k2i < 8 ? k2i : 48 + k2i;
      cf2 tw = twl[(k2*n2)&63];
      float2 z = z1[k2i][k3];
      zr = fmaf(z.x, tw.x, fmaf(z.y, tw.y, zr));
      zi = fmaf(z.y, tw.x, fmaf(-z.x, tw.y, zi));
    }
    z2[n2][k3] = make_float2(zr, zi);
  }
  __syncthreads();
  // k3 -> n3 (Re - Im folded into p/q with 1/64^3), + cos_phase corner, store
  int n3 = t & 63;
  int n2base = (t >> 6) * 16;
  float p[8], q[8];
  #pragma unroll
  for (int k3=0;k3<8;k3++){
    cf2 pq = pql[(k3*n3)&63];
    p[k3] = pq.x; q[k3] = pq.y;
  }
  float* orow = out + ((size_t)bc*64 + n1)*4096;
  bool corner = (n1 < 8) && (n3 < 8);
  const float* cpr = cp + (size_t)bc*512 + n1*64 + n3;
  #pragma unroll
  for (int j=0;j<16;j++){
    int n2 = n2base + j;
    float v = 0.f;
    #pragma unroll
    for (int k3=0;k3<8;k3++){
      float2 z = z2[n2][k3];
      v = fmaf(z.x, p[k3], fmaf(z.y, q[k3], v));
    }
    if (corner && n2 < 8) v *= cpr[n2*8];
    orow[n2*64 + n3] = v;
  }
}

// ---------------- launch ----------------
extern "C" void kernel_launch(void* const* d_in, const int* in_sizes, int n_in,
                              void* d_out, int out_size, void* d_ws, size_t ws_size,
                              hipStream_t stream) {
  (void)in_sizes; (void)n_in; (void)out_size; (void)ws_size;
  const float* x  = (const float*)d_in[0];
  const float* w1 = (const float*)d_in[1];
  const float* w2 = (const float*)d_in[2];
  const float* w3 = (const float*)d_in[3];
  const float* w4 = (const float*)d_in[4];
  float* out = (float*)d_out;
  char* ws = (char*)d_ws;
  float2* y2g = (float2*)ws;                                   // 8 MiB
  float*  xh  = (float*)(ws + (8u<<20));                       // 1 MiB
  float*  cp  = (float*)(ws + (9u<<20));                       // 256 KiB
  float*  mh  = (float*)(ws + (9u<<20) + (256u<<10));          // 1 MiB

  k_fwd   <<<8192, 256, 0, stream>>>(x, y2g);
  k_fwd_n1<<< 128, 256, 0, stream>>>(y2g, xh, cp);
  k_mix   <<<2048, 256, 0, stream>>>(xh, w1, w2, w3, w4, mh);
  k_inv   <<<8192, 256, 0, stream>>>(mh, cp, out);
}

// Round 3
// 287.679 us; speedup vs baseline: 1.0710x; 1.0314x over previous
//
#include <hip/hip_runtime.h>
#include <math.h>

// ---------------- compile-time 64-point twiddle tables ----------------
struct cf2 { float x, y; };
struct TW64 { float c[64], s[64]; };
struct CF2T { cf2 v[64]; };

constexpr double PI_D = 3.14159265358979323846264338327950288;

constexpr double tsin(double x){
  double x2 = x*x, r = x, t = x;
  t *= -x2/6.0;   r += t;
  t *= -x2/20.0;  r += t;
  t *= -x2/42.0;  r += t;
  t *= -x2/72.0;  r += t;
  t *= -x2/110.0; r += t;
  t *= -x2/156.0; r += t;
  t *= -x2/210.0; r += t;
  t *= -x2/272.0; r += t;
  return r;
}
constexpr double tcos(double x){
  double x2 = x*x, r = 1.0, t = 1.0;
  t *= -x2/2.0;   r += t;
  t *= -x2/12.0;  r += t;
  t *= -x2/30.0;  r += t;
  t *= -x2/56.0;  r += t;
  t *= -x2/90.0;  r += t;
  t *= -x2/132.0; r += t;
  t *= -x2/182.0; r += t;
  t *= -x2/240.0; r += t;
  return r;
}
constexpr double ang_cos(int j){
  int r = j & 15, q = (j >> 4) & 3;
  double a = PI_D/32.0 * r;
  double cc = tcos(a), ss = tsin(a);
  return q==0 ? cc : q==1 ? -ss : q==2 ? -cc : ss;
}
constexpr double ang_sin(int j){
  int r = j & 15, q = (j >> 4) & 3;
  double a = PI_D/32.0 * r;
  double cc = tcos(a), ss = tsin(a);
  return q==0 ? ss : q==1 ? cc : q==2 ? -ss : -cc;
}
constexpr TW64 make_tw(){
  TW64 t{};
  for (int j=0;j<64;j++){ t.c[j] = (float)ang_cos(j); t.s[j] = (float)ang_sin(j); }
  return t;
}
constexpr CF2T make_twi(){
  CF2T r{};
  for (int j=0;j<64;j++){ r.v[j].x = (float)ang_cos(j); r.v[j].y = (float)ang_sin(j); }
  return r;
}
constexpr CF2T make_pq(){
  CF2T r{};
  for (int j=0;j<64;j++){
    double c = ang_cos(j), s = ang_sin(j);
    r.v[j].x = (float)((c + s) / 262144.0);  // (cos+sin)/64^3
    r.v[j].y = (float)((s - c) / 262144.0);  // (sin-cos)/64^3
  }
  return r;
}

constexpr TW64 TWct = make_tw();        // constant-folded literals (unrolled loops)
__constant__ CF2T TWIdev = make_twi();  // runtime (c,s) lookups
__constant__ CF2T PQdev  = make_pq();   // inverse last-stage coefficients, scale folded

// ---------------- K1: forward n3->k3 (8 modes) and n2->k2 (16 modes) ----------------
// grid = (b*64+ci)*32 + n1pair  (4096 blocks), 256 threads, 2 n1-planes per block
// out: y2g[bc][n1][k2i*8+k3] float2   (8 MiB)

template<int G>   // computes k3 = G..G+3, acc = {r0,i0,r1,i1,...}
__device__ __forceinline__ void stageA4(const float* __restrict__ row, float* a){
  #pragma unroll
  for (int m=0;m<8;m++) a[m]=0.f;
  #pragma unroll
  for (int qd=0;qd<16;qd++){
    float4 v = ((const float4*)row)[qd];   // row 16B-aligned (stride 72 floats)
    float xv[4] = {v.x, v.y, v.z, v.w};
    #pragma unroll
    for (int u=0;u<4;u++){
      int n3 = qd*4 + u;
      #pragma unroll
      for (int m=0;m<4;m++){
        a[2*m  ] = fmaf(xv[u],  TWct.c[((G+m)*n3)&63], a[2*m  ]);
        a[2*m+1] = fmaf(xv[u], -TWct.s[((G+m)*n3)&63], a[2*m+1]);
      }
    }
  }
}

__global__ __launch_bounds__(256) void k_fwd(const float* __restrict__ x, float2* __restrict__ y2g){
  __shared__ alignas(16) float xt[2][64][72];   // [n1l][n2][n3], stride 72 -> 16B rows
  __shared__ alignas(16) float2 y1[2][8][66];   // [n1l][k3][n2]
  __shared__ cf2 twl[64];
  int bid = blockIdx.x;
  int pp = bid & 31, ci_b = bid >> 5;   // n1 = pp*2 + n1l
  int t = threadIdx.x;
  if (t < 64) twl[t] = TWIdev.v[t];

  // coalesced staging: 32 KB = 2 planes
  const float4* src = (const float4*)(x + (size_t)(ci_b*64 + pp*2)*4096);
  #pragma unroll
  for (int j=0;j<8;j++){
    int q = t + j*256;
    float4 v = src[q];
    int n1l = q >> 10, r = q & 1023;
    int n2 = r >> 4, n3q = r & 15;
    float* d = &xt[n1l][n2][n3q*4];
    d[0]=v.x; d[1]=v.y; d[2]=v.z; d[3]=v.w;
  }
  __syncthreads();

  // stage A: n3 -> k3; thread (n1l = t>>7, g = (t>>6)&1, n2 = t&63) does k3 = 4g..4g+3
  {
    int n2 = t & 63, g = (t>>6)&1, n1l = t>>7;
    const float* row = &xt[n1l][n2][0];
    float a[8];
    if (g==0) stageA4<0>(row, a); else stageA4<4>(row, a);
    #pragma unroll
    for (int m=0;m<4;m++) y1[n1l][4*g+m][n2] = make_float2(a[2*m], a[2*m+1]);
  }
  __syncthreads();

  // stage B: n2 -> k2 via rotation recurrence; thread (n1l = t>>7, s = t&127)
  {
    int n1l = t>>7, s = t&127, k2i = s>>3, k3 = s&7;
    int k2 = k2i<8 ? k2i : 48+k2i;
    cf2 st = twl[k2];
    float c = 1.f, sn = 0.f, ar = 0.f, ai = 0.f;
    const float4* yrow = (const float4*)&y1[n1l][k3][0];
    #pragma unroll
    for (int m=0;m<32;m++){
      float4 v = yrow[m];            // (y[2m].x y[2m].y y[2m+1].x y[2m+1].y)
      ar = fmaf(v.x, c, fmaf(v.y, sn, ar));
      ai = fmaf(v.y, c, fmaf(-v.x, sn, ai));
      float c2 = fmaf(c, st.x, -(sn*st.y));
      float s2 = fmaf(sn, st.x,  c*st.y);
      ar = fmaf(v.z, c2, fmaf(v.w, s2, ar));
      ai = fmaf(v.w, c2, fmaf(-v.z, s2, ai));
      c  = fmaf(c2, st.x, -(s2*st.y));
      sn = fmaf(s2, st.x,  c2*st.y);
    }
    y2g[(size_t)(ci_b*64 + pp*2 + n1l)*128 + s] = make_float2(ar, ai);
  }
}

// ---------------- K2: forward n1->k1 (16 modes) + xh + cos_phase ----------------
// grid = bc*16 + k2i (2048 blocks), 256 threads
__global__ __launch_bounds__(256) void k_fwd_n1(const float2* __restrict__ y2g,
                                                float* __restrict__ xh, float* __restrict__ cp){
  __shared__ alignas(16) float2 yl[64][8];   // [n1][k3] 4 KB
  __shared__ cf2 twl[64];
  int bc = blockIdx.x >> 4, k2i = blockIdx.x & 15;
  int t = threadIdx.x;
  if (t < 64) twl[t] = TWIdev.v[t];
  {
    int n1 = t >> 2, q = t & 3;
    const float4* s4 = (const float4*)(y2g + ((size_t)(bc*64 + n1)*128 + k2i*8));
    ((float4*)&yl[n1][0])[q] = s4[q];
  }
  __syncthreads();
  int half = t&1, k3 = (t>>1)&7, k1i = t>>4;
  int k1 = k1i<8 ? k1i : 48+k1i;
  cf2 st = twl[k1];
  cf2 cs = twl[(k1*half*32)&63];
  float c = cs.x, sn = cs.y, ar = 0.f, ai = 0.f;
  #pragma unroll
  for (int i=0;i<32;i++){
    float2 y = yl[half*32+i][k3];
    ar = fmaf(y.x, c, fmaf(y.y, sn, ar));
    ai = fmaf(y.y, c, fmaf(-y.x, sn, ai));
    float c2 = fmaf(c, st.x, -(sn*st.y));
    sn = fmaf(sn, st.x,  c*st.y);
    c = c2;
  }
  ar += __shfl_xor(ar, 1, 64);
  ai += __shfl_xor(ai, 1, 64);
  if (half == 0){
    float vxh = ar - ai;                    // Re - Im
    xh[(size_t)(bc*16 + k1i)*128 + k2i*8 + k3] = vxh;
    if (k1i < 8 && k2i < 8){
      cf2 tw = twl[(k1i + k2i + k3) & 63];  // e^{i*2pi*(k1+k2+k3)/64} * conj(X)
      float vxhf = ar*(tw.x - tw.y) + ai*(tw.x + tw.y);
      cp[(size_t)bc*512 + k1i*64 + k2i*8 + k3] = cosf(atan2f(vxhf, vxh));
    }
  }
}

// ---------------- K3: per-mode channel mixing (einsum bixyz,ioxyz->boxyz) ----------------
// grid = (blk*64+co)*8 + k1l (2048 blocks), 256 threads
__global__ __launch_bounds__(256) void k_mix(const float* __restrict__ xh,
    const float* __restrict__ w1, const float* __restrict__ w2,
    const float* __restrict__ w3, const float* __restrict__ w4,
    float* __restrict__ mh){
  __shared__ alignas(16) float xs[2][64][64];   // [b][ci][k2l*8+k3]
  __shared__ alignas(16) float wsh[64][64];     // [ci][k2l*8+k3]
  __shared__ float ps[2][128];
  int bid = blockIdx.x;
  int k1l = bid & 7, co = (bid >> 3) & 63, blk = bid >> 9;
  const float* w = (blk==0) ? w1 : (blk==1) ? w2 : (blk==2) ? w3 : w4;
  int k1i = k1l + ((blk & 1) << 3);
  int k2off = (blk & 2) ? 64 : 0;
  int t = threadIdx.x;
  #pragma unroll
  for (int jj=0;jj<4;jj++){
    int idx = t + jj*256;               // 0..1023
    int ci = idx >> 4, kq = idx & 15;
    float4 v = *(const float4*)(w + (size_t)(ci*64 + co)*512 + k1l*64 + kq*4);
    ((float4*)&wsh[ci][0])[kq] = v;
  }
  #pragma unroll
  for (int jj=0;jj<8;jj++){
    int idx = t + jj*256;               // 0..2047
    int b = idx >> 10, ci = (idx >> 4) & 63, kq = idx & 15;
    float4 v = *(const float4*)(xh + (size_t)((b*64 + ci)*16 + k1i)*128 + k2off + kq*4);
    ((float4*)&xs[b][ci][0])[kq] = v;
  }
  __syncthreads();
  int half = t >> 7, o = t & 127, b = o >> 6, kk = o & 63;
  float acc = 0.f;
  #pragma unroll 8
  for (int i=0;i<32;i++){
    int ci = half*32 + i;
    acc = fmaf(xs[b][ci][kk], wsh[ci][kk], acc);
  }
  ps[half][o] = acc;
  __syncthreads();
  if (t < 128){
    int b2 = t >> 6, kk2 = t & 63;
    mh[(size_t)((b2*64 + co)*16 + k1i)*128 + k2off + kk2] = ps[0][t] + ps[1][t];
  }
}

// ---------------- K4: fused inverse DHT (sparse modes) + cos_phase + store ----------------
// grid = (b*64+co)*64 + n1 (8192 blocks), 256 threads
__global__ __launch_bounds__(256) void k_inv(const float* __restrict__ mh,
                                             const float* __restrict__ cp,
                                             float* __restrict__ out){
  __shared__ alignas(16) float ml[2048];
  __shared__ alignas(16) float2 z1[16][8];
  __shared__ alignas(16) float2 z2[64][8];
  __shared__ cf2 twl[64];
  __shared__ cf2 pql[64];
  int bid = blockIdx.x;
  int n1 = bid & 63, bc = bid >> 6;
  int t = threadIdx.x;
  if (t < 64){ twl[t] = TWIdev.v[t]; pql[t] = PQdev.v[t]; }
  const float4* src = (const float4*)(mh + (size_t)bc * 2048);
  ((float4*)ml)[t]       = src[t];
  ((float4*)ml)[t + 256] = src[t + 256];
  __syncthreads();
  // k1 -> n1 (this block's n1 only)
  if (t < 128){
    float zr = 0.f, zi = 0.f;
    #pragma unroll
    for (int k1i=0;k1i<16;k1i++){
      int k1 = k1i < 8 ? k1i : 48 + k1i;
      cf2 tw = TWIdev.v[(k1*n1)&63];   // uniform -> s_load
      float m = ml[k1i*128 + t];
      zr = fmaf(m, tw.x, zr);
      zi = fmaf(m, -tw.y, zi);
    }
    z1[t>>3][t&7] = make_float2(zr, zi);
  }
  __syncthreads();
  // k2 -> n2 via rotation recurrence (two chains: k2=0..7 and k2=56..63)
  #pragma unroll
  for (int jo=0;jo<2;jo++){
    int o = t + jo*256;
    int n2 = o >> 3, k3 = o & 7;
    cf2 st = twl[n2];
    float zr = 0.f, zi = 0.f;
    float c = 1.f, sn = 0.f;
    #pragma unroll
    for (int k2i=0;k2i<8;k2i++){
      float2 z = z1[k2i][k3];
      zr = fmaf(z.x, c, fmaf(z.y, sn, zr));
      zi = fmaf(z.y, c, fmaf(-z.x, sn, zi));
      float c2 = fmaf(c, st.x, -(sn*st.y));
      sn = fmaf(sn, st.x, c*st.y);
      c = c2;
    }
    cf2 cs = twl[(56*n2)&63];
    c = cs.x; sn = cs.y;
    #pragma unroll
    for (int k2i=8;k2i<16;k2i++){
      float2 z = z1[k2i][k3];
      zr = fmaf(z.x, c, fmaf(z.y, sn, zr));
      zi = fmaf(z.y, c, fmaf(-z.x, sn, zi));
      float c2 = fmaf(c, st.x, -(sn*st.y));
      sn = fmaf(sn, st.x, c*st.y);
      c = c2;
    }
    z2[n2][k3] = make_float2(zr, zi);
  }
  __syncthreads();
  // k3 -> n3 (Re - Im folded into p/q with 1/64^3), + cos_phase corner, store
  int n3 = t & 63;
  int n2base = (t >> 6) * 16;
  float p[8], q[8];
  #pragma unroll
  for (int k3=0;k3<8;k3++){
    cf2 pq = pql[(k3*n3)&63];
    p[k3] = pq.x; q[k3] = pq.y;
  }
  float* orow = out + ((size_t)bc*64 + n1)*4096;
  bool corner = (n1 < 8) && (n3 < 8);
  const float* cpr = cp + (size_t)bc*512 + n1*64 + n3;
  #pragma unroll
  for (int j=0;j<16;j++){
    int n2 = n2base + j;
    const float4* zr4 = (const float4*)&z2[n2][0];
    float4 u0 = zr4[0], u1 = zr4[1], u2 = zr4[2], u3 = zr4[3];
    float v;
    v = fmaf(u0.x, p[0], u0.y*q[0]);
    v = fmaf(u0.z, p[1], fmaf(u0.w, q[1], v));
    v = fmaf(u1.x, p[2], fmaf(u1.y, q[2], v));
    v = fmaf(u1.z, p[3], fmaf(u1.w, q[3], v));
    v = fmaf(u2.x, p[4], fmaf(u2.y, q[4], v));
    v = fmaf(u2.z, p[5], fmaf(u2.w, q[5], v));
    v = fmaf(u3.x, p[6], fmaf(u3.y, q[6], v));
    v = fmaf(u3.z, p[7], fmaf(u3.w, q[7], v));
    if (corner && n2 < 8) v *= cpr[n2*8];
    orow[n2*64 + n3] = v;
  }
}

// ---------------- launch ----------------
extern "C" void kernel_launch(void* const* d_in, const int* in_sizes, int n_in,
                              void* d_out, int out_size, void* d_ws, size_t ws_size,
                              hipStream_t stream) {
  (void)in_sizes; (void)n_in; (void)out_size; (void)ws_size;
  const float* x  = (const float*)d_in[0];
  const float* w1 = (const float*)d_in[1];
  const float* w2 = (const float*)d_in[2];
  const float* w3 = (const float*)d_in[3];
  const float* w4 = (const float*)d_in[4];
  float* out = (float*)d_out;
  char* ws = (char*)d_ws;
  float2* y2g = (float2*)ws;                                   // 8 MiB
  float*  xh  = (float*)(ws + (8u<<20));                       // 1 MiB
  float*  cp  = (float*)(ws + (9u<<20));                       // 256 KiB
  float*  mh  = (float*)(ws + (9u<<20) + (256u<<10));          // 1 MiB

  k_fwd   <<<4096, 256, 0, stream>>>(x, y2g);
  k_fwd_n1<<<2048, 256, 0, stream>>>(y2g, xh, cp);
  k_mix   <<<2048, 256, 0, stream>>>(xh, w1, w2, w3, w4, mh);
  k_inv   <<<8192, 256, 0, stream>>>(mh, cp, out);
}